// Round 1
// baseline (1913.173 us; speedup 1.0000x reference)
//
#include <hip/hip_runtime.h>
#include <stdint.h>

#define TOKENS 8192
#define HIDDEN 4096
constexpr float EPS = 1e-6f;
constexpr float FP8_MAX = 448.0f;

using f32x4 = __attribute__((ext_vector_type(4))) float;

typedef __attribute__((address_space(3))) uint32_t lds_u32_t;
typedef const __attribute__((address_space(1))) uint32_t glb_u32_t;

// ---------------- fp8 pack helper (OCP e4m3fn, RNE + saturate) ----------------
__device__ inline uint32_t pack_fp8x4(float a, float b, float c, float d) {
    int w = 0;
    w = __builtin_amdgcn_cvt_pk_fp8_f32(a, b, w, false); // bytes 0,1
    w = __builtin_amdgcn_cvt_pk_fp8_f32(c, d, w, true);  // bytes 2,3
    return (uint32_t)w;
}

// ---------------- block reductions (4 waves of 64) ----------------
__device__ inline float block_sum(float v, float* sh, int tid) {
#pragma unroll
    for (int o = 32; o > 0; o >>= 1) v += __shfl_xor(v, o, 64);
    if ((tid & 63) == 0) sh[tid >> 6] = v;
    __syncthreads();
    return sh[0] + sh[1] + sh[2] + sh[3];
}
__device__ inline float block_max(float v, float* sh, int tid) {
#pragma unroll
    for (int o = 32; o > 0; o >>= 1) v = fmaxf(v, __shfl_xor(v, o, 64));
    if ((tid & 63) == 0) sh[tid >> 6] = v;
    __syncthreads();
    return fmaxf(fmaxf(sh[0], sh[1]), fmaxf(sh[2], sh[3]));
}

// ---------------- weight quantization: Wq = fp8(W / s) ----------------
__launch_bounds__(256)
__global__ void quant_weights(const float* __restrict__ Ws,
                              const float* __restrict__ w_scales,
                              uint8_t* __restrict__ Wq) {
    size_t idx = ((size_t)blockIdx.x * 256 + threadIdx.x) * 8;
    int tensor = (int)(idx / ((size_t)HIDDEN * HIDDEN));
    float inv = 1.0f / w_scales[tensor];
    const float4* src = (const float4*)(Ws + idx);
    float4 v0 = src[0], v1 = src[1];
    uint2 out;
    out.x = pack_fp8x4(v0.x * inv, v0.y * inv, v0.z * inv, v0.w * inv);
    out.y = pack_fp8x4(v1.x * inv, v1.y * inv, v1.z * inv, v1.w * inv);
    *(uint2*)(Wq + idx) = out;
}

// ---------------- relu + rmsnorm + dynamic quant (layer 0 input) ----------------
__launch_bounds__(256)
__global__ void relu_rms_quant(const float* __restrict__ x,
                               const float* __restrict__ nw,   // norm_w row 0
                               float* __restrict__ resid,
                               uint8_t* __restrict__ yq,
                               float* __restrict__ ascale) {
    __shared__ float sh1[4], sh2[4];
    const int row = blockIdx.x, tid = threadIdx.x;
    const float* xr = x + (size_t)row * HIDDEN;
    float* rr = resid + (size_t)row * HIDDEN;

    float4 v[4];
    float ss = 0.f;
#pragma unroll
    for (int c = 0; c < 4; ++c) {
        float4 t = *(const float4*)(xr + c * 1024 + tid * 4);
        t.x = fmaxf(t.x, 0.f); t.y = fmaxf(t.y, 0.f);
        t.z = fmaxf(t.z, 0.f); t.w = fmaxf(t.w, 0.f);
        v[c] = t;
        ss += t.x * t.x + t.y * t.y + t.z * t.z + t.w * t.w;
        *(float4*)(rr + c * 1024 + tid * 4) = t;
    }
    ss = block_sum(ss, sh1, tid);
    float rstd = 1.0f / sqrtf(ss * (1.0f / HIDDEN) + EPS);

    float4 y[4];
    float amax = 0.f;
#pragma unroll
    for (int c = 0; c < 4; ++c) {
        float4 w = *(const float4*)(nw + c * 1024 + tid * 4);
        y[c].x = v[c].x * rstd * w.x; amax = fmaxf(amax, fabsf(y[c].x));
        y[c].y = v[c].y * rstd * w.y; amax = fmaxf(amax, fabsf(y[c].y));
        y[c].z = v[c].z * rstd * w.z; amax = fmaxf(amax, fabsf(y[c].z));
        y[c].w = v[c].w * rstd * w.w; amax = fmaxf(amax, fabsf(y[c].w));
    }
    amax = block_max(amax, sh2, tid);
    float s = fmaxf(amax / FP8_MAX, 1e-12f);
    if (tid == 0) ascale[row] = s;
    float inv = 1.0f / s;
#pragma unroll
    for (int c = 0; c < 4; ++c) {
        uint32_t p = pack_fp8x4(y[c].x * inv, y[c].y * inv, y[c].z * inv, y[c].w * inv);
        *(uint32_t*)(yq + (size_t)row * HIDDEN + c * 1024 + tid * 4) = p;
    }
}

// ---------------- rmsnorm + dynamic quant (between layers) ----------------
__launch_bounds__(256)
__global__ void rms_quant(const float* __restrict__ resid,
                          const float* __restrict__ nw,
                          uint8_t* __restrict__ yq,
                          float* __restrict__ ascale) {
    __shared__ float sh1[4], sh2[4];
    const int row = blockIdx.x, tid = threadIdx.x;
    const float* rr = resid + (size_t)row * HIDDEN;

    float4 v[4];
    float ss = 0.f;
#pragma unroll
    for (int c = 0; c < 4; ++c) {
        float4 t = *(const float4*)(rr + c * 1024 + tid * 4);
        v[c] = t;
        ss += t.x * t.x + t.y * t.y + t.z * t.z + t.w * t.w;
    }
    ss = block_sum(ss, sh1, tid);
    float rstd = 1.0f / sqrtf(ss * (1.0f / HIDDEN) + EPS);

    float4 y[4];
    float amax = 0.f;
#pragma unroll
    for (int c = 0; c < 4; ++c) {
        float4 w = *(const float4*)(nw + c * 1024 + tid * 4);
        y[c].x = v[c].x * rstd * w.x; amax = fmaxf(amax, fabsf(y[c].x));
        y[c].y = v[c].y * rstd * w.y; amax = fmaxf(amax, fabsf(y[c].y));
        y[c].z = v[c].z * rstd * w.z; amax = fmaxf(amax, fabsf(y[c].z));
        y[c].w = v[c].w * rstd * w.w; amax = fmaxf(amax, fabsf(y[c].w));
    }
    amax = block_max(amax, sh2, tid);
    float s = fmaxf(amax / FP8_MAX, 1e-12f);
    if (tid == 0) ascale[row] = s;
    float inv = 1.0f / s;
#pragma unroll
    for (int c = 0; c < 4; ++c) {
        uint32_t p = pack_fp8x4(y[c].x * inv, y[c].y * inv, y[c].z * inv, y[c].w * inv);
        *(uint32_t*)(yq + (size_t)row * HIDDEN + c * 1024 + tid * 4) = p;
    }
}

// ---------------- final rmsnorm -> f32 output ----------------
__launch_bounds__(256)
__global__ void rms_final(const float* __restrict__ resid,
                          const float* __restrict__ nw,
                          float* __restrict__ out) {
    __shared__ float sh1[4];
    const int row = blockIdx.x, tid = threadIdx.x;
    const float* rr = resid + (size_t)row * HIDDEN;

    float4 v[4];
    float ss = 0.f;
#pragma unroll
    for (int c = 0; c < 4; ++c) {
        float4 t = *(const float4*)(rr + c * 1024 + tid * 4);
        v[c] = t;
        ss += t.x * t.x + t.y * t.y + t.z * t.z + t.w * t.w;
    }
    ss = block_sum(ss, sh1, tid);
    float rstd = 1.0f / sqrtf(ss * (1.0f / HIDDEN) + EPS);

#pragma unroll
    for (int c = 0; c < 4; ++c) {
        float4 w = *(const float4*)(nw + c * 1024 + tid * 4);
        float4 o;
        o.x = v[c].x * rstd * w.x;
        o.y = v[c].y * rstd * w.y;
        o.z = v[c].z * rstd * w.z;
        o.w = v[c].w * rstd * w.w;
        *(float4*)(out + (size_t)row * HIDDEN + c * 1024 + tid * 4) = o;
    }
}

// ---------------- fp8 GEMM: resid += a_scale[t]*w_scale * (Aq @ Bq^T) ----------------
// A: yq [TOKENS][HIDDEN] fp8.  B: Wq [HIDDEN(out)][HIDDEN(k)] fp8 (Linear: C = A @ B^T).
#define BM 128
#define BN 128
#define BK 64

__launch_bounds__(256)
__global__ void gemm_fp8(const uint8_t* __restrict__ Aq,
                         const uint8_t* __restrict__ Bq,
                         const float* __restrict__ ascale,
                         const float* __restrict__ wscale_p,
                         float* __restrict__ resid) {
    __shared__ __align__(16) uint8_t sA[BM * BK];
    __shared__ __align__(16) uint8_t sB[BN * BK];
    __shared__ float s_as[BM];

    const int tid = threadIdx.x;
    const int bid = blockIdx.x;
    const int nbn = HIDDEN / BN;   // 32
    const int bm = bid / nbn, bn = bid % nbn;
    const int brow = bm * BM, bcol = bn * BN;

    const int wave = tid >> 6, lane = tid & 63;
    const int wm = wave >> 1, wn = wave & 1;
    const int lr = lane & 15, lk = lane >> 4;

    if (tid < BM) s_as[tid] = ascale[brow + tid];

    f32x4 acc[4][4] = {};

    const uint8_t* aSrc = Aq + (size_t)brow * HIDDEN;
    const uint8_t* bSrc = Bq + (size_t)bcol * HIDDEN;

    // staging: linear LDS layout [128 rows][64 bytes]; wave w, lane l, chunk c
    // covers LDS bytes c*4096 + w*1024 + l*16  (global_load_lds: uniform base + lane*16)
    const int off0 = tid * 16;          // chunk 0 linear offset for this thread
    const int r0 = off0 >> 6, c0 = off0 & 63;
    const int off1 = 4096 + tid * 16;   // chunk 1
    const int r1 = off1 >> 6, c1 = off1 & 63;
    uint8_t* ldsA0 = &sA[(wave) * 1024];
    uint8_t* ldsA1 = &sA[4096 + (wave) * 1024];
    uint8_t* ldsB0 = &sB[(wave) * 1024];
    uint8_t* ldsB1 = &sB[4096 + (wave) * 1024];

    for (int k0 = 0; k0 < HIDDEN; k0 += BK) {
        __syncthreads();
        __builtin_amdgcn_global_load_lds((glb_u32_t*)(aSrc + (size_t)r0 * HIDDEN + k0 + c0),
                                         (lds_u32_t*)ldsA0, 16, 0, 0);
        __builtin_amdgcn_global_load_lds((glb_u32_t*)(aSrc + (size_t)r1 * HIDDEN + k0 + c1),
                                         (lds_u32_t*)ldsA1, 16, 0, 0);
        __builtin_amdgcn_global_load_lds((glb_u32_t*)(bSrc + (size_t)r0 * HIDDEN + k0 + c0),
                                         (lds_u32_t*)ldsB0, 16, 0, 0);
        __builtin_amdgcn_global_load_lds((glb_u32_t*)(bSrc + (size_t)r1 * HIDDEN + k0 + c1),
                                         (lds_u32_t*)ldsB1, 16, 0, 0);
        __syncthreads();
#pragma unroll
        for (int kk = 0; kk < 2; ++kk) {
            long a[4], b[4];
#pragma unroll
            for (int m = 0; m < 4; ++m)
                a[m] = *(const long*)&sA[(wm * 64 + m * 16 + lr) * BK + kk * 32 + lk * 8];
#pragma unroll
            for (int n = 0; n < 4; ++n)
                b[n] = *(const long*)&sB[(wn * 64 + n * 16 + lr) * BK + kk * 32 + lk * 8];
#pragma unroll
            for (int m = 0; m < 4; ++m)
#pragma unroll
                for (int n = 0; n < 4; ++n)
                    acc[m][n] = __builtin_amdgcn_mfma_f32_16x16x32_fp8_fp8(a[m], b[n], acc[m][n], 0, 0, 0);
        }
    }

    const float wsc = *wscale_p;
#pragma unroll
    for (int m = 0; m < 4; ++m) {
        const int lrow = wm * 64 + m * 16 + lk * 4;  // local row base of this lane's 4 rows
#pragma unroll
        for (int n = 0; n < 4; ++n) {
            const int col = bcol + wn * 64 + n * 16 + lr;
#pragma unroll
            for (int r = 0; r < 4; ++r) {
                const int row = brow + lrow + r;
                const float alpha = s_as[lrow + r] * wsc;
                const size_t o = (size_t)row * HIDDEN + col;
                resid[o] += acc[m][n][r] * alpha;
            }
        }
    }
}

// ---------------- launch ----------------
extern "C" void kernel_launch(void* const* d_in, const int* in_sizes, int n_in,
                              void* d_out, int out_size, void* d_ws, size_t ws_size,
                              hipStream_t stream) {
    const float* x   = (const float*)d_in[0];
    const float* nw  = (const float*)d_in[1];
    const float* Ws  = (const float*)d_in[2];
    const float* wsc = (const float*)d_in[3];
    float* out = (float*)d_out;

    uint8_t* ws = (uint8_t*)d_ws;
    float*   resid  = (float*)ws;                                  // 128 MiB
    uint8_t* yq     = ws + (size_t)TOKENS * HIDDEN * 4;            // 32 MiB
    uint8_t* Wq     = yq + (size_t)TOKENS * HIDDEN;                // 48 MiB
    float*   ascale = (float*)(Wq + (size_t)3 * HIDDEN * HIDDEN);  // 32 KiB

    // quantize weights (3 * H * H elements, 8 per thread)
    quant_weights<<<(3 * (size_t)HIDDEN * HIDDEN) / 2048, 256, 0, stream>>>(Ws, wsc, Wq);

    // relu + rmsnorm(norm_w[0]) + quant
    relu_rms_quant<<<TOKENS, 256, 0, stream>>>(x, nw, resid, yq, ascale);

    for (int i = 0; i < 3; ++i) {
        gemm_fp8<<<(TOKENS / BM) * (HIDDEN / BN), 256, 0, stream>>>(
            yq, Wq + (size_t)i * HIDDEN * HIDDEN, ascale, wsc + i, resid);
        if (i < 2)
            rms_quant<<<TOKENS, 256, 0, stream>>>(resid, nw + (size_t)(i + 1) * HIDDEN, yq, ascale);
        else
            rms_final<<<TOKENS, 256, 0, stream>>>(resid, nw + (size_t)3 * HIDDEN, out);
    }
}

// Round 2
// 940.373 us; speedup vs baseline: 2.0345x; 2.0345x over previous
//
#include <hip/hip_runtime.h>
#include <stdint.h>

#define TOKENS 8192
#define HIDDEN 4096
constexpr float EPS = 1e-6f;
constexpr float FP8_MAX = 448.0f;

using f32x4 = __attribute__((ext_vector_type(4))) float;
using i64x2 = __attribute__((ext_vector_type(2))) long;

typedef __attribute__((address_space(3))) uint32_t lds_u32_t;
typedef const __attribute__((address_space(1))) uint32_t glb_u32_t;

// Permute within each 64B K-granule: old byte o = [kk(1)|lk(2)|b(3)] ->
// new = [lk(2)|kk(1)|b(3)], so a lane's (lk) fragment for kk=0,1 is one
// contiguous 16B granule. Applied when PRODUCING yq / Wq.
__device__ inline size_t perm64(size_t o) {
    return (o & ~(size_t)63) | (((o >> 3) & 3) << 4) | (((o >> 5) & 1) << 3) | (o & 7);
}

// ---------------- fp8 pack helper (OCP e4m3fn, RNE + saturate) ----------------
__device__ inline uint32_t pack_fp8x4(float a, float b, float c, float d) {
    int w = 0;
    w = __builtin_amdgcn_cvt_pk_fp8_f32(a, b, w, false); // bytes 0,1
    w = __builtin_amdgcn_cvt_pk_fp8_f32(c, d, w, true);  // bytes 2,3
    return (uint32_t)w;
}

// ---------------- block reductions (4 waves of 64) ----------------
__device__ inline float block_sum(float v, float* sh, int tid) {
#pragma unroll
    for (int o = 32; o > 0; o >>= 1) v += __shfl_xor(v, o, 64);
    if ((tid & 63) == 0) sh[tid >> 6] = v;
    __syncthreads();
    return sh[0] + sh[1] + sh[2] + sh[3];
}
__device__ inline float block_max(float v, float* sh, int tid) {
#pragma unroll
    for (int o = 32; o > 0; o >>= 1) v = fmaxf(v, __shfl_xor(v, o, 64));
    if ((tid & 63) == 0) sh[tid >> 6] = v;
    __syncthreads();
    return fmaxf(fmaxf(sh[0], sh[1]), fmaxf(sh[2], sh[3]));
}

// ---------------- weight quantization: Wq = fp8(W / s), permuted layout ----------------
__launch_bounds__(256)
__global__ void quant_weights(const float* __restrict__ Ws,
                              const float* __restrict__ w_scales,
                              uint8_t* __restrict__ Wq) {
    size_t idx = ((size_t)blockIdx.x * 256 + threadIdx.x) * 8;
    int tensor = (int)(idx / ((size_t)HIDDEN * HIDDEN));
    float inv = 1.0f / w_scales[tensor];
    const float4* src = (const float4*)(Ws + idx);
    float4 v0 = src[0], v1 = src[1];
    uint2 out;
    out.x = pack_fp8x4(v0.x * inv, v0.y * inv, v0.z * inv, v0.w * inv);
    out.y = pack_fp8x4(v1.x * inv, v1.y * inv, v1.z * inv, v1.w * inv);
    *(uint2*)(Wq + perm64(idx)) = out;   // idx is 8B-aligned: b-bits contiguous
}

// ---------------- relu + rmsnorm + dynamic quant (layer 0 input) ----------------
__launch_bounds__(256)
__global__ void relu_rms_quant(const float* __restrict__ x,
                               const float* __restrict__ nw,   // norm_w row 0
                               float* __restrict__ resid,
                               uint8_t* __restrict__ yq,
                               float* __restrict__ ascale) {
    __shared__ float sh1[4], sh2[4];
    const int row = blockIdx.x, tid = threadIdx.x;
    const float* xr = x + (size_t)row * HIDDEN;
    float* rr = resid + (size_t)row * HIDDEN;

    float4 v[4];
    float ss = 0.f;
#pragma unroll
    for (int c = 0; c < 4; ++c) {
        float4 t = *(const float4*)(xr + c * 1024 + tid * 4);
        t.x = fmaxf(t.x, 0.f); t.y = fmaxf(t.y, 0.f);
        t.z = fmaxf(t.z, 0.f); t.w = fmaxf(t.w, 0.f);
        v[c] = t;
        ss += t.x * t.x + t.y * t.y + t.z * t.z + t.w * t.w;
        *(float4*)(rr + c * 1024 + tid * 4) = t;
    }
    ss = block_sum(ss, sh1, tid);
    float rstd = 1.0f / sqrtf(ss * (1.0f / HIDDEN) + EPS);

    float4 y[4];
    float amax = 0.f;
#pragma unroll
    for (int c = 0; c < 4; ++c) {
        float4 w = *(const float4*)(nw + c * 1024 + tid * 4);
        y[c].x = v[c].x * rstd * w.x; amax = fmaxf(amax, fabsf(y[c].x));
        y[c].y = v[c].y * rstd * w.y; amax = fmaxf(amax, fabsf(y[c].y));
        y[c].z = v[c].z * rstd * w.z; amax = fmaxf(amax, fabsf(y[c].z));
        y[c].w = v[c].w * rstd * w.w; amax = fmaxf(amax, fabsf(y[c].w));
    }
    amax = block_max(amax, sh2, tid);
    float s = fmaxf(amax / FP8_MAX, 1e-12f);
    if (tid == 0) ascale[row] = s;
    float inv = 1.0f / s;
#pragma unroll
    for (int c = 0; c < 4; ++c) {
        uint32_t p = pack_fp8x4(y[c].x * inv, y[c].y * inv, y[c].z * inv, y[c].w * inv);
        *(uint32_t*)(yq + perm64((size_t)row * HIDDEN + c * 1024 + tid * 4)) = p;
    }
}

// ---------------- rmsnorm + dynamic quant (between layers) ----------------
__launch_bounds__(256)
__global__ void rms_quant(const float* __restrict__ resid,
                          const float* __restrict__ nw,
                          uint8_t* __restrict__ yq,
                          float* __restrict__ ascale) {
    __shared__ float sh1[4], sh2[4];
    const int row = blockIdx.x, tid = threadIdx.x;
    const float* rr = resid + (size_t)row * HIDDEN;

    float4 v[4];
    float ss = 0.f;
#pragma unroll
    for (int c = 0; c < 4; ++c) {
        float4 t = *(const float4*)(rr + c * 1024 + tid * 4);
        v[c] = t;
        ss += t.x * t.x + t.y * t.y + t.z * t.z + t.w * t.w;
    }
    ss = block_sum(ss, sh1, tid);
    float rstd = 1.0f / sqrtf(ss * (1.0f / HIDDEN) + EPS);

    float4 y[4];
    float amax = 0.f;
#pragma unroll
    for (int c = 0; c < 4; ++c) {
        float4 w = *(const float4*)(nw + c * 1024 + tid * 4);
        y[c].x = v[c].x * rstd * w.x; amax = fmaxf(amax, fabsf(y[c].x));
        y[c].y = v[c].y * rstd * w.y; amax = fmaxf(amax, fabsf(y[c].y));
        y[c].z = v[c].z * rstd * w.z; amax = fmaxf(amax, fabsf(y[c].z));
        y[c].w = v[c].w * rstd * w.w; amax = fmaxf(amax, fabsf(y[c].w));
    }
    amax = block_max(amax, sh2, tid);
    float s = fmaxf(amax / FP8_MAX, 1e-12f);
    if (tid == 0) ascale[row] = s;
    float inv = 1.0f / s;
#pragma unroll
    for (int c = 0; c < 4; ++c) {
        uint32_t p = pack_fp8x4(y[c].x * inv, y[c].y * inv, y[c].z * inv, y[c].w * inv);
        *(uint32_t*)(yq + perm64((size_t)row * HIDDEN + c * 1024 + tid * 4)) = p;
    }
}

// ---------------- final rmsnorm -> f32 output ----------------
__launch_bounds__(256)
__global__ void rms_final(const float* __restrict__ resid,
                          const float* __restrict__ nw,
                          float* __restrict__ out) {
    __shared__ float sh1[4];
    const int row = blockIdx.x, tid = threadIdx.x;
    const float* rr = resid + (size_t)row * HIDDEN;

    float4 v[4];
    float ss = 0.f;
#pragma unroll
    for (int c = 0; c < 4; ++c) {
        float4 t = *(const float4*)(rr + c * 1024 + tid * 4);
        v[c] = t;
        ss += t.x * t.x + t.y * t.y + t.z * t.z + t.w * t.w;
    }
    ss = block_sum(ss, sh1, tid);
    float rstd = 1.0f / sqrtf(ss * (1.0f / HIDDEN) + EPS);

#pragma unroll
    for (int c = 0; c < 4; ++c) {
        float4 w = *(const float4*)(nw + c * 1024 + tid * 4);
        float4 o;
        o.x = v[c].x * rstd * w.x;
        o.y = v[c].y * rstd * w.y;
        o.z = v[c].z * rstd * w.z;
        o.w = v[c].w * rstd * w.w;
        *(float4*)(out + (size_t)row * HIDDEN + c * 1024 + tid * 4) = o;
    }
}

// ---------------- fp8 GEMM: resid += a_scale[t]*w_scale * (Aq @ Bq^T) ----------------
// Aq/Bq are stored in perm64 layout: row-major [rows][4096], each 64B K-granule
// reordered [lk:16B][kk:8B] so a lane's fragment (both kk) is one b128 read.
// LDS: linear [128 rows][64B]; 16B-granule index XOR-swizzled by (row>>1)&3 via
// pre-swizzled global source (global_load_lds writes linearly).
#define BM 128
#define BN 128
#define BK 64

__launch_bounds__(256)
__global__ void gemm_fp8(const uint8_t* __restrict__ Aq,
                         const uint8_t* __restrict__ Bq,
                         const float* __restrict__ ascale,
                         const float* __restrict__ wscale_p,
                         float* __restrict__ resid) {
    __shared__ __align__(16) uint8_t sA[BM * BK];
    __shared__ __align__(16) uint8_t sB[BN * BK];
    __shared__ float s_as[BM];

    const int tid = threadIdx.x;
    // XCD-chunked bijective swizzle (grid = 2048 = 8 * 256)
    int bid = blockIdx.x;
    bid = (bid & 7) * 256 + (bid >> 3);
    const int nbn = HIDDEN / BN;   // 32
    const int bm = bid / nbn, bn = bid % nbn;
    const int brow = bm * BM, bcol = bn * BN;

    const int wave = tid >> 6, lane = tid & 63;
    const int wm = wave >> 1, wn = wave & 1;
    const int lr = lane & 15, lk = lane >> 4;

    if (tid < BM) s_as[tid] = ascale[brow + tid];

    f32x4 acc[4][4] = {};

    const uint8_t* aSrc = Aq + (size_t)brow * HIDDEN;
    const uint8_t* bSrc = Bq + (size_t)bcol * HIDDEN;

    // Stager: thread covers LDS rows r and r+64, granule g (16B).
    // LDS[r][g] must hold global granule g ^ ((r>>1)&3); note ((r+64)>>1)&3 == (r>>1)&3.
    const int r_st = tid >> 2;            // 0..63
    const int g_st = tid & 3;
    const int gsrc = g_st ^ ((r_st >> 1) & 3);
    const size_t aOff0 = (size_t)r_st * HIDDEN + gsrc * 16;
    const size_t aOff1 = (size_t)(r_st + 64) * HIDDEN + gsrc * 16;
    uint8_t* ldsA0 = &sA[wave * 1024];           // + lane*16 implicit
    uint8_t* ldsA1 = &sA[4096 + wave * 1024];
    uint8_t* ldsB0 = &sB[wave * 1024];
    uint8_t* ldsB1 = &sB[4096 + wave * 1024];

    // Reader: fragment rows + swizzled granule (gA = lk ^ ((row>>1)&3))
    int rowOffA[4], rowOffB[4];
#pragma unroll
    for (int m = 0; m < 4; ++m) {
        int ra = wm * 64 + m * 16 + lr;
        rowOffA[m] = ra * 64 + (lk ^ ((ra >> 1) & 3)) * 16;
        int rb = wn * 64 + m * 16 + lr;
        rowOffB[m] = rb * 64 + (lk ^ ((rb >> 1) & 3)) * 16;
    }

    for (int k0 = 0; k0 < HIDDEN; k0 += BK) {
        __syncthreads();
        __builtin_amdgcn_global_load_lds((glb_u32_t*)(aSrc + aOff0 + k0),
                                         (lds_u32_t*)ldsA0, 16, 0, 0);
        __builtin_amdgcn_global_load_lds((glb_u32_t*)(aSrc + aOff1 + k0),
                                         (lds_u32_t*)ldsA1, 16, 0, 0);
        __builtin_amdgcn_global_load_lds((glb_u32_t*)(bSrc + aOff0 + k0),
                                         (lds_u32_t*)ldsB0, 16, 0, 0);
        __builtin_amdgcn_global_load_lds((glb_u32_t*)(bSrc + aOff1 + k0),
                                         (lds_u32_t*)ldsB1, 16, 0, 0);
        __syncthreads();

        long a0[4], a1[4], b0[4], b1[4];
#pragma unroll
        for (int m = 0; m < 4; ++m) {
            i64x2 av = *(const i64x2*)&sA[rowOffA[m]];
            a0[m] = av.x; a1[m] = av.y;
        }
#pragma unroll
        for (int n = 0; n < 4; ++n) {
            i64x2 bv = *(const i64x2*)&sB[rowOffB[n]];
            b0[n] = bv.x; b1[n] = bv.y;
        }
#pragma unroll
        for (int m = 0; m < 4; ++m)
#pragma unroll
            for (int n = 0; n < 4; ++n)
                acc[m][n] = __builtin_amdgcn_mfma_f32_16x16x32_fp8_fp8(a0[m], b0[n], acc[m][n], 0, 0, 0);
#pragma unroll
        for (int m = 0; m < 4; ++m)
#pragma unroll
            for (int n = 0; n < 4; ++n)
                acc[m][n] = __builtin_amdgcn_mfma_f32_16x16x32_fp8_fp8(a1[m], b1[n], acc[m][n], 0, 0, 0);
    }

    const float wsc = *wscale_p;
#pragma unroll
    for (int m = 0; m < 4; ++m) {
        const int lrow = wm * 64 + m * 16 + lk * 4;  // local row base of this lane's 4 rows
#pragma unroll
        for (int n = 0; n < 4; ++n) {
            const int col = bcol + wn * 64 + n * 16 + lr;
#pragma unroll
            for (int r = 0; r < 4; ++r) {
                const int row = brow + lrow + r;
                const float alpha = s_as[lrow + r] * wsc;
                const size_t o = (size_t)row * HIDDEN + col;
                resid[o] += acc[m][n][r] * alpha;
            }
        }
    }
}

// ---------------- launch ----------------
extern "C" void kernel_launch(void* const* d_in, const int* in_sizes, int n_in,
                              void* d_out, int out_size, void* d_ws, size_t ws_size,
                              hipStream_t stream) {
    const float* x   = (const float*)d_in[0];
    const float* nw  = (const float*)d_in[1];
    const float* Ws  = (const float*)d_in[2];
    const float* wsc = (const float*)d_in[3];
    float* out = (float*)d_out;

    uint8_t* ws = (uint8_t*)d_ws;
    float*   resid  = (float*)ws;                                  // 128 MiB
    uint8_t* yq     = ws + (size_t)TOKENS * HIDDEN * 4;            // 32 MiB
    uint8_t* Wq     = yq + (size_t)TOKENS * HIDDEN;                // 48 MiB
    float*   ascale = (float*)(Wq + (size_t)3 * HIDDEN * HIDDEN);  // 32 KiB

    // quantize weights (3 * H * H elements, 8 per thread)
    quant_weights<<<(3 * (size_t)HIDDEN * HIDDEN) / 2048, 256, 0, stream>>>(Ws, wsc, Wq);

    // relu + rmsnorm(norm_w[0]) + quant
    relu_rms_quant<<<TOKENS, 256, 0, stream>>>(x, nw, resid, yq, ascale);

    for (int i = 0; i < 3; ++i) {
        gemm_fp8<<<(TOKENS / BM) * (HIDDEN / BN), 256, 0, stream>>>(
            yq, Wq + (size_t)i * HIDDEN * HIDDEN, ascale, wsc + i, resid);
        if (i < 2)
            rms_quant<<<TOKENS, 256, 0, stream>>>(resid, nw + (size_t)(i + 1) * HIDDEN, yq, ascale);
        else
            rms_final<<<TOKENS, 256, 0, stream>>>(resid, nw + (size_t)3 * HIDDEN, out);
    }
}

// Round 3
// 810.445 us; speedup vs baseline: 2.3606x; 1.1603x over previous
//
#include <hip/hip_runtime.h>
#include <stdint.h>

#define TOKENS 8192
#define HIDDEN 4096
constexpr float EPS = 1e-6f;
constexpr float FP8_MAX = 448.0f;

using f32x4  = __attribute__((ext_vector_type(4))) float;
using f32x16 = __attribute__((ext_vector_type(16))) float;
using i32x4  = __attribute__((ext_vector_type(4))) int;
using i32x8  = __attribute__((ext_vector_type(8))) int;

typedef __attribute__((address_space(3))) uint32_t lds_u32_t;
typedef const __attribute__((address_space(1))) uint32_t glb_u32_t;

// ---------------- fp8 pack helper (OCP e4m3fn, RNE + saturate) ----------------
__device__ inline uint32_t pack_fp8x4(float a, float b, float c, float d) {
    int w = 0;
    w = __builtin_amdgcn_cvt_pk_fp8_f32(a, b, w, false); // bytes 0,1
    w = __builtin_amdgcn_cvt_pk_fp8_f32(c, d, w, true);  // bytes 2,3
    return (uint32_t)w;
}

// ---------------- block reductions (4 waves of 64) ----------------
__device__ inline float block_sum(float v, float* sh, int tid) {
#pragma unroll
    for (int o = 32; o > 0; o >>= 1) v += __shfl_xor(v, o, 64);
    if ((tid & 63) == 0) sh[tid >> 6] = v;
    __syncthreads();
    return sh[0] + sh[1] + sh[2] + sh[3];
}
__device__ inline float block_max(float v, float* sh, int tid) {
#pragma unroll
    for (int o = 32; o > 0; o >>= 1) v = fmaxf(v, __shfl_xor(v, o, 64));
    if ((tid & 63) == 0) sh[tid >> 6] = v;
    __syncthreads();
    return fmaxf(fmaxf(sh[0], sh[1]), fmaxf(sh[2], sh[3]));
}

// ---------------- weight quantization: Wq = fp8(W / s), linear layout ----------------
__launch_bounds__(256)
__global__ void quant_weights(const float* __restrict__ Ws,
                              const float* __restrict__ w_scales,
                              uint8_t* __restrict__ Wq) {
    size_t idx = ((size_t)blockIdx.x * 256 + threadIdx.x) * 8;
    int tensor = (int)(idx / ((size_t)HIDDEN * HIDDEN));
    float inv = 1.0f / w_scales[tensor];
    const float4* src = (const float4*)(Ws + idx);
    float4 v0 = src[0], v1 = src[1];
    uint2 out;
    out.x = pack_fp8x4(v0.x * inv, v0.y * inv, v0.z * inv, v0.w * inv);
    out.y = pack_fp8x4(v1.x * inv, v1.y * inv, v1.z * inv, v1.w * inv);
    *(uint2*)(Wq + idx) = out;
}

// ---------------- relu + rmsnorm + dynamic quant (layer 0 input) ----------------
__launch_bounds__(256)
__global__ void relu_rms_quant(const float* __restrict__ x,
                               const float* __restrict__ nw,   // norm_w row 0
                               float* __restrict__ resid,
                               uint8_t* __restrict__ yq,
                               float* __restrict__ ascale) {
    __shared__ float sh1[4], sh2[4];
    const int row = blockIdx.x, tid = threadIdx.x;
    const float* xr = x + (size_t)row * HIDDEN;
    float* rr = resid + (size_t)row * HIDDEN;

    float4 v[4];
    float ss = 0.f;
#pragma unroll
    for (int c = 0; c < 4; ++c) {
        float4 t = *(const float4*)(xr + c * 1024 + tid * 4);
        t.x = fmaxf(t.x, 0.f); t.y = fmaxf(t.y, 0.f);
        t.z = fmaxf(t.z, 0.f); t.w = fmaxf(t.w, 0.f);
        v[c] = t;
        ss += t.x * t.x + t.y * t.y + t.z * t.z + t.w * t.w;
        *(float4*)(rr + c * 1024 + tid * 4) = t;
    }
    ss = block_sum(ss, sh1, tid);
    float rstd = 1.0f / sqrtf(ss * (1.0f / HIDDEN) + EPS);

    float4 y[4];
    float amax = 0.f;
#pragma unroll
    for (int c = 0; c < 4; ++c) {
        float4 w = *(const float4*)(nw + c * 1024 + tid * 4);
        y[c].x = v[c].x * rstd * w.x; amax = fmaxf(amax, fabsf(y[c].x));
        y[c].y = v[c].y * rstd * w.y; amax = fmaxf(amax, fabsf(y[c].y));
        y[c].z = v[c].z * rstd * w.z; amax = fmaxf(amax, fabsf(y[c].z));
        y[c].w = v[c].w * rstd * w.w; amax = fmaxf(amax, fabsf(y[c].w));
    }
    amax = block_max(amax, sh2, tid);
    float s = fmaxf(amax / FP8_MAX, 1e-12f);
    if (tid == 0) ascale[row] = s;
    float inv = 1.0f / s;
#pragma unroll
    for (int c = 0; c < 4; ++c) {
        uint32_t p = pack_fp8x4(y[c].x * inv, y[c].y * inv, y[c].z * inv, y[c].w * inv);
        *(uint32_t*)(yq + (size_t)row * HIDDEN + c * 1024 + tid * 4) = p;
    }
}

// ---------------- rmsnorm + dynamic quant (between layers) ----------------
__launch_bounds__(256)
__global__ void rms_quant(const float* __restrict__ resid,
                          const float* __restrict__ nw,
                          uint8_t* __restrict__ yq,
                          float* __restrict__ ascale) {
    __shared__ float sh1[4], sh2[4];
    const int row = blockIdx.x, tid = threadIdx.x;
    const float* rr = resid + (size_t)row * HIDDEN;

    float4 v[4];
    float ss = 0.f;
#pragma unroll
    for (int c = 0; c < 4; ++c) {
        float4 t = *(const float4*)(rr + c * 1024 + tid * 4);
        v[c] = t;
        ss += t.x * t.x + t.y * t.y + t.z * t.z + t.w * t.w;
    }
    ss = block_sum(ss, sh1, tid);
    float rstd = 1.0f / sqrtf(ss * (1.0f / HIDDEN) + EPS);

    float4 y[4];
    float amax = 0.f;
#pragma unroll
    for (int c = 0; c < 4; ++c) {
        float4 w = *(const float4*)(nw + c * 1024 + tid * 4);
        y[c].x = v[c].x * rstd * w.x; amax = fmaxf(amax, fabsf(y[c].x));
        y[c].y = v[c].y * rstd * w.y; amax = fmaxf(amax, fabsf(y[c].y));
        y[c].z = v[c].z * rstd * w.z; amax = fmaxf(amax, fabsf(y[c].z));
        y[c].w = v[c].w * rstd * w.w; amax = fmaxf(amax, fabsf(y[c].w));
    }
    amax = block_max(amax, sh2, tid);
    float s = fmaxf(amax / FP8_MAX, 1e-12f);
    if (tid == 0) ascale[row] = s;
    float inv = 1.0f / s;
#pragma unroll
    for (int c = 0; c < 4; ++c) {
        uint32_t p = pack_fp8x4(y[c].x * inv, y[c].y * inv, y[c].z * inv, y[c].w * inv);
        *(uint32_t*)(yq + (size_t)row * HIDDEN + c * 1024 + tid * 4) = p;
    }
}

// ---------------- final rmsnorm -> f32 output ----------------
__launch_bounds__(256)
__global__ void rms_final(const float* __restrict__ resid,
                          const float* __restrict__ nw,
                          float* __restrict__ out) {
    __shared__ float sh1[4];
    const int row = blockIdx.x, tid = threadIdx.x;
    const float* rr = resid + (size_t)row * HIDDEN;

    float4 v[4];
    float ss = 0.f;
#pragma unroll
    for (int c = 0; c < 4; ++c) {
        float4 t = *(const float4*)(rr + c * 1024 + tid * 4);
        v[c] = t;
        ss += t.x * t.x + t.y * t.y + t.z * t.z + t.w * t.w;
    }
    ss = block_sum(ss, sh1, tid);
    float rstd = 1.0f / sqrtf(ss * (1.0f / HIDDEN) + EPS);

#pragma unroll
    for (int c = 0; c < 4; ++c) {
        float4 w = *(const float4*)(nw + c * 1024 + tid * 4);
        float4 o;
        o.x = v[c].x * rstd * w.x;
        o.y = v[c].y * rstd * w.y;
        o.z = v[c].z * rstd * w.z;
        o.w = v[c].w * rstd * w.w;
        *(float4*)(out + (size_t)row * HIDDEN + c * 1024 + tid * 4) = o;
    }
}

// ---------------- fp8 GEMM via MX-scaled MFMA (unit scales) ----------------
// resid += a_scale[t]*w_scale * (Aq @ Bq^T), Aq/Bq linear row-major fp8.
// mfma_scale_f32_32x32x64_f8f6f4 with e8m0 scale 0x7F (=2^0) computes raw q_a.q_w.
// LDS linear [128 rows][64B], 16B-granule XOR-swizzle g^((row>>1)&3) applied on the
// global SOURCE address (global_load_lds writes linearly) and on ds_read addresses.
#define BM 128
#define BN 128
#define BK 64

__launch_bounds__(256)
__global__ void gemm_fp8(const uint8_t* __restrict__ Aq,
                         const uint8_t* __restrict__ Bq,
                         const float* __restrict__ ascale,
                         const float* __restrict__ wscale_p,
                         float* __restrict__ resid) {
    __shared__ __align__(16) uint8_t sA[BM * BK];
    __shared__ __align__(16) uint8_t sB[BN * BK];
    __shared__ float s_as[BM];

    const int tid = threadIdx.x;
    // XCD-chunked bijective swizzle (grid = 2048 = 8 * 256)
    int bid = blockIdx.x;
    bid = (bid & 7) * 256 + (bid >> 3);
    const int nbn = HIDDEN / BN;   // 32
    const int bm = bid / nbn, bn = bid % nbn;
    const int brow = bm * BM, bcol = bn * BN;

    const int wave = tid >> 6, lane = tid & 63;
    const int wm = wave >> 1, wn = wave & 1;
    const int lr = lane & 31;      // row within 32x32 tile
    const int lh = lane >> 5;      // k-half (which 32B k-block)

    if (tid < BM) s_as[tid] = ascale[brow + tid];

    f32x16 acc[2][2] = {};

    const uint8_t* aSrc = Aq + (size_t)brow * HIDDEN;
    const uint8_t* bSrc = Bq + (size_t)bcol * HIDDEN;

    // Stager: thread covers LDS rows r and r+64, granule g (16B).
    // LDS[r][g] holds global granule g ^ ((r>>1)&3); ((r+64)>>1)&3 == (r>>1)&3.
    const int r_st = tid >> 2;            // 0..63
    const int g_st = tid & 3;
    const int gsrc = g_st ^ ((r_st >> 1) & 3);
    const size_t off0 = (size_t)r_st * HIDDEN + gsrc * 16;
    const size_t off1 = (size_t)(r_st + 64) * HIDDEN + gsrc * 16;
    uint8_t* ldsA0 = &sA[wave * 1024];           // + lane*16 implicit
    uint8_t* ldsA1 = &sA[4096 + wave * 1024];
    uint8_t* ldsB0 = &sB[wave * 1024];
    uint8_t* ldsB1 = &sB[4096 + wave * 1024];

    // Reader: lane fragment = 32 contiguous k-bytes of one row, as two b128s
    // at swizzled granules (2*lh)^s and (2*lh+1)^s.
    int offA[2][2], offB[2][2];
#pragma unroll
    for (int m = 0; m < 2; ++m) {
        int ra = wm * 64 + m * 32 + lr;
        int sa_ = (ra >> 1) & 3;
        offA[m][0] = ra * 64 + ((2 * lh + 0) ^ sa_) * 16;
        offA[m][1] = ra * 64 + ((2 * lh + 1) ^ sa_) * 16;
        int rb = wn * 64 + m * 32 + lr;
        int sb_ = (rb >> 1) & 3;
        offB[m][0] = rb * 64 + ((2 * lh + 0) ^ sb_) * 16;
        offB[m][1] = rb * 64 + ((2 * lh + 1) ^ sb_) * 16;
    }

    const int UNIT = 0x7F7F7F7F;  // e8m0 scale = 2^0 in all bytes

    for (int k0 = 0; k0 < HIDDEN; k0 += BK) {
        __syncthreads();
        __builtin_amdgcn_global_load_lds((glb_u32_t*)(aSrc + off0 + k0),
                                         (lds_u32_t*)ldsA0, 16, 0, 0);
        __builtin_amdgcn_global_load_lds((glb_u32_t*)(aSrc + off1 + k0),
                                         (lds_u32_t*)ldsA1, 16, 0, 0);
        __builtin_amdgcn_global_load_lds((glb_u32_t*)(bSrc + off0 + k0),
                                         (lds_u32_t*)ldsB0, 16, 0, 0);
        __builtin_amdgcn_global_load_lds((glb_u32_t*)(bSrc + off1 + k0),
                                         (lds_u32_t*)ldsB1, 16, 0, 0);
        __syncthreads();

        i32x8 a[2], b[2];
#pragma unroll
        for (int m = 0; m < 2; ++m) {
            i32x4 lo = *(const i32x4*)&sA[offA[m][0]];
            i32x4 hi = *(const i32x4*)&sA[offA[m][1]];
            a[m] = __builtin_shufflevector(lo, hi, 0, 1, 2, 3, 4, 5, 6, 7);
        }
#pragma unroll
        for (int n = 0; n < 2; ++n) {
            i32x4 lo = *(const i32x4*)&sB[offB[n][0]];
            i32x4 hi = *(const i32x4*)&sB[offB[n][1]];
            b[n] = __builtin_shufflevector(lo, hi, 0, 1, 2, 3, 4, 5, 6, 7);
        }
#pragma unroll
        for (int m = 0; m < 2; ++m)
#pragma unroll
            for (int n = 0; n < 2; ++n)
                acc[m][n] = __builtin_amdgcn_mfma_scale_f32_32x32x64_f8f6f4(
                    a[m], b[n], acc[m][n], 0, 0, 0, UNIT, 0, UNIT);
    }

    const float wsc = *wscale_p;
#pragma unroll
    for (int m = 0; m < 2; ++m)
#pragma unroll
        for (int n = 0; n < 2; ++n) {
            const int col = bcol + wn * 64 + n * 32 + lr;
#pragma unroll
            for (int i = 0; i < 16; ++i) {
                const int rl = (i & 3) + 8 * (i >> 2) + 4 * lh;
                const int row_local = wm * 64 + m * 32 + rl;
                const float alpha = s_as[row_local] * wsc;
                const size_t o = (size_t)(brow + row_local) * HIDDEN + col;
                resid[o] += acc[m][n][i] * alpha;
            }
        }
}

// ---------------- launch ----------------
extern "C" void kernel_launch(void* const* d_in, const int* in_sizes, int n_in,
                              void* d_out, int out_size, void* d_ws, size_t ws_size,
                              hipStream_t stream) {
    const float* x   = (const float*)d_in[0];
    const float* nw  = (const float*)d_in[1];
    const float* Ws  = (const float*)d_in[2];
    const float* wsc = (const float*)d_in[3];
    float* out = (float*)d_out;

    uint8_t* ws = (uint8_t*)d_ws;
    float*   resid  = (float*)ws;                                  // 128 MiB
    uint8_t* yq     = ws + (size_t)TOKENS * HIDDEN * 4;            // 32 MiB
    uint8_t* Wq     = yq + (size_t)TOKENS * HIDDEN;                // 48 MiB
    float*   ascale = (float*)(Wq + (size_t)3 * HIDDEN * HIDDEN);  // 32 KiB

    // quantize weights (3 * H * H elements, 8 per thread)
    quant_weights<<<(3 * (size_t)HIDDEN * HIDDEN) / 2048, 256, 0, stream>>>(Ws, wsc, Wq);

    // relu + rmsnorm(norm_w[0]) + quant
    relu_rms_quant<<<TOKENS, 256, 0, stream>>>(x, nw, resid, yq, ascale);

    for (int i = 0; i < 3; ++i) {
        gemm_fp8<<<(TOKENS / BM) * (HIDDEN / BN), 256, 0, stream>>>(
            yq, Wq + (size_t)i * HIDDEN * HIDDEN, ascale, wsc + i, resid);
        if (i < 2)
            rms_quant<<<TOKENS, 256, 0, stream>>>(resid, nw + (size_t)(i + 1) * HIDDEN, yq, ascale);
        else
            rms_final<<<TOKENS, 256, 0, stream>>>(resid, nw + (size_t)3 * HIDDEN, out);
    }
}

// Round 4
// 788.553 us; speedup vs baseline: 2.4262x; 1.0278x over previous
//
#include <hip/hip_runtime.h>
#include <stdint.h>

#define TOKENS 8192
#define HIDDEN 4096
constexpr float EPS = 1e-6f;
constexpr float FP8_MAX = 448.0f;

using f32x4  = __attribute__((ext_vector_type(4))) float;
using f32x16 = __attribute__((ext_vector_type(16))) float;
using i32x4  = __attribute__((ext_vector_type(4))) int;
using i32x8  = __attribute__((ext_vector_type(8))) int;

typedef __attribute__((address_space(3))) uint32_t lds_u32_t;
typedef const __attribute__((address_space(1))) uint32_t glb_u32_t;

// ---------------- fp8 pack helper (OCP e4m3fn, RNE + saturate) ----------------
__device__ inline uint32_t pack_fp8x4(float a, float b, float c, float d) {
    int w = 0;
    w = __builtin_amdgcn_cvt_pk_fp8_f32(a, b, w, false); // bytes 0,1
    w = __builtin_amdgcn_cvt_pk_fp8_f32(c, d, w, true);  // bytes 2,3
    return (uint32_t)w;
}

// ---------------- block reductions (4 waves of 64) ----------------
__device__ inline float block_sum(float v, float* sh, int tid) {
#pragma unroll
    for (int o = 32; o > 0; o >>= 1) v += __shfl_xor(v, o, 64);
    if ((tid & 63) == 0) sh[tid >> 6] = v;
    __syncthreads();
    return sh[0] + sh[1] + sh[2] + sh[3];
}
__device__ inline float block_max(float v, float* sh, int tid) {
#pragma unroll
    for (int o = 32; o > 0; o >>= 1) v = fmaxf(v, __shfl_xor(v, o, 64));
    if ((tid & 63) == 0) sh[tid >> 6] = v;
    __syncthreads();
    return fmaxf(fmaxf(sh[0], sh[1]), fmaxf(sh[2], sh[3]));
}

// ---------------- weight quantization: Wq = fp8(W / s), linear layout ----------------
__launch_bounds__(256)
__global__ void quant_weights(const float* __restrict__ Ws,
                              const float* __restrict__ w_scales,
                              uint8_t* __restrict__ Wq) {
    size_t idx = ((size_t)blockIdx.x * 256 + threadIdx.x) * 8;
    int tensor = (int)(idx / ((size_t)HIDDEN * HIDDEN));
    float inv = 1.0f / w_scales[tensor];
    const float4* src = (const float4*)(Ws + idx);
    float4 v0 = src[0], v1 = src[1];
    uint2 out;
    out.x = pack_fp8x4(v0.x * inv, v0.y * inv, v0.z * inv, v0.w * inv);
    out.y = pack_fp8x4(v1.x * inv, v1.y * inv, v1.z * inv, v1.w * inv);
    *(uint2*)(Wq + idx) = out;
}

// ---------------- relu + rmsnorm + dynamic quant (layer 0 input) ----------------
__launch_bounds__(256)
__global__ void relu_rms_quant(const float* __restrict__ x,
                               const float* __restrict__ nw,   // norm_w row 0
                               float* __restrict__ resid,
                               uint8_t* __restrict__ yq,
                               float* __restrict__ ascale) {
    __shared__ float sh1[4], sh2[4];
    const int row = blockIdx.x, tid = threadIdx.x;
    const float* xr = x + (size_t)row * HIDDEN;
    float* rr = resid + (size_t)row * HIDDEN;

    float4 v[4];
    float ss = 0.f;
#pragma unroll
    for (int c = 0; c < 4; ++c) {
        float4 t = *(const float4*)(xr + c * 1024 + tid * 4);
        t.x = fmaxf(t.x, 0.f); t.y = fmaxf(t.y, 0.f);
        t.z = fmaxf(t.z, 0.f); t.w = fmaxf(t.w, 0.f);
        v[c] = t;
        ss += t.x * t.x + t.y * t.y + t.z * t.z + t.w * t.w;
        *(float4*)(rr + c * 1024 + tid * 4) = t;
    }
    ss = block_sum(ss, sh1, tid);
    float rstd = 1.0f / sqrtf(ss * (1.0f / HIDDEN) + EPS);

    float4 y[4];
    float amax = 0.f;
#pragma unroll
    for (int c = 0; c < 4; ++c) {
        float4 w = *(const float4*)(nw + c * 1024 + tid * 4);
        y[c].x = v[c].x * rstd * w.x; amax = fmaxf(amax, fabsf(y[c].x));
        y[c].y = v[c].y * rstd * w.y; amax = fmaxf(amax, fabsf(y[c].y));
        y[c].z = v[c].z * rstd * w.z; amax = fmaxf(amax, fabsf(y[c].z));
        y[c].w = v[c].w * rstd * w.w; amax = fmaxf(amax, fabsf(y[c].w));
    }
    amax = block_max(amax, sh2, tid);
    float s = fmaxf(amax / FP8_MAX, 1e-12f);
    if (tid == 0) ascale[row] = s;
    float inv = 1.0f / s;
#pragma unroll
    for (int c = 0; c < 4; ++c) {
        uint32_t p = pack_fp8x4(y[c].x * inv, y[c].y * inv, y[c].z * inv, y[c].w * inv);
        *(uint32_t*)(yq + (size_t)row * HIDDEN + c * 1024 + tid * 4) = p;
    }
}

// ---------------- rmsnorm + dynamic quant (between layers) ----------------
__launch_bounds__(256)
__global__ void rms_quant(const float* __restrict__ resid,
                          const float* __restrict__ nw,
                          uint8_t* __restrict__ yq,
                          float* __restrict__ ascale) {
    __shared__ float sh1[4], sh2[4];
    const int row = blockIdx.x, tid = threadIdx.x;
    const float* rr = resid + (size_t)row * HIDDEN;

    float4 v[4];
    float ss = 0.f;
#pragma unroll
    for (int c = 0; c < 4; ++c) {
        float4 t = *(const float4*)(rr + c * 1024 + tid * 4);
        v[c] = t;
        ss += t.x * t.x + t.y * t.y + t.z * t.z + t.w * t.w;
    }
    ss = block_sum(ss, sh1, tid);
    float rstd = 1.0f / sqrtf(ss * (1.0f / HIDDEN) + EPS);

    float4 y[4];
    float amax = 0.f;
#pragma unroll
    for (int c = 0; c < 4; ++c) {
        float4 w = *(const float4*)(nw + c * 1024 + tid * 4);
        y[c].x = v[c].x * rstd * w.x; amax = fmaxf(amax, fabsf(y[c].x));
        y[c].y = v[c].y * rstd * w.y; amax = fmaxf(amax, fabsf(y[c].y));
        y[c].z = v[c].z * rstd * w.z; amax = fmaxf(amax, fabsf(y[c].z));
        y[c].w = v[c].w * rstd * w.w; amax = fmaxf(amax, fabsf(y[c].w));
    }
    amax = block_max(amax, sh2, tid);
    float s = fmaxf(amax / FP8_MAX, 1e-12f);
    if (tid == 0) ascale[row] = s;
    float inv = 1.0f / s;
#pragma unroll
    for (int c = 0; c < 4; ++c) {
        uint32_t p = pack_fp8x4(y[c].x * inv, y[c].y * inv, y[c].z * inv, y[c].w * inv);
        *(uint32_t*)(yq + (size_t)row * HIDDEN + c * 1024 + tid * 4) = p;
    }
}

// ---------------- final rmsnorm -> f32 output ----------------
__launch_bounds__(256)
__global__ void rms_final(const float* __restrict__ resid,
                          const float* __restrict__ nw,
                          float* __restrict__ out) {
    __shared__ float sh1[4];
    const int row = blockIdx.x, tid = threadIdx.x;
    const float* rr = resid + (size_t)row * HIDDEN;

    float4 v[4];
    float ss = 0.f;
#pragma unroll
    for (int c = 0; c < 4; ++c) {
        float4 t = *(const float4*)(rr + c * 1024 + tid * 4);
        v[c] = t;
        ss += t.x * t.x + t.y * t.y + t.z * t.z + t.w * t.w;
    }
    ss = block_sum(ss, sh1, tid);
    float rstd = 1.0f / sqrtf(ss * (1.0f / HIDDEN) + EPS);

#pragma unroll
    for (int c = 0; c < 4; ++c) {
        float4 w = *(const float4*)(nw + c * 1024 + tid * 4);
        float4 o;
        o.x = v[c].x * rstd * w.x;
        o.y = v[c].y * rstd * w.y;
        o.z = v[c].z * rstd * w.z;
        o.w = v[c].w * rstd * w.w;
        *(float4*)(out + (size_t)row * HIDDEN + c * 1024 + tid * 4) = o;
    }
}

// ---------------- fp8 GEMM via MX-scaled MFMA, 2-phase double-buffered ----------------
// resid += a_scale[t]*w_scale * (Aq @ Bq^T), Aq/Bq linear row-major fp8.
// Per K-step: issue next tile's global_load_lds FIRST, then ds_read+MFMA current
// tile, then one __syncthreads() (compiler drains vmcnt(0) before it — loads had
// the whole compute phase to fly). One barrier per K-step.
#define BM 128
#define BN 128
#define BK 64

__launch_bounds__(256)
__global__ void gemm_fp8(const uint8_t* __restrict__ Aq,
                         const uint8_t* __restrict__ Bq,
                         const float* __restrict__ ascale,
                         const float* __restrict__ wscale_p,
                         float* __restrict__ resid) {
    __shared__ __align__(16) uint8_t sA[2][BM * BK];
    __shared__ __align__(16) uint8_t sB[2][BN * BK];
    __shared__ float s_as[BM];

    const int tid = threadIdx.x;
    // XCD-chunked bijective swizzle (grid = 2048 = 8 * 256)
    int bid = blockIdx.x;
    bid = (bid & 7) * 256 + (bid >> 3);
    const int nbn = HIDDEN / BN;   // 32
    const int bm = bid / nbn, bn = bid % nbn;
    const int brow = bm * BM, bcol = bn * BN;

    const int wave = tid >> 6, lane = tid & 63;
    const int wm = wave >> 1, wn = wave & 1;
    const int lr = lane & 31;      // row within 32x32 tile
    const int lh = lane >> 5;      // k-half (which 32B k-block)

    if (tid < BM) s_as[tid] = ascale[brow + tid];

    f32x16 acc[2][2] = {};

    const uint8_t* aSrc = Aq + (size_t)brow * HIDDEN;
    const uint8_t* bSrc = Bq + (size_t)bcol * HIDDEN;

    // Stager: thread covers LDS rows r and r+64, granule g (16B).
    // LDS[r][g] holds global granule g ^ ((r>>1)&3); ((r+64)>>1)&3 == (r>>1)&3.
    const int r_st = tid >> 2;            // 0..63
    const int g_st = tid & 3;
    const int gsrc = g_st ^ ((r_st >> 1) & 3);
    const size_t off0 = (size_t)r_st * HIDDEN + gsrc * 16;
    const size_t off1 = (size_t)(r_st + 64) * HIDDEN + gsrc * 16;
    const int lds0 = wave * 1024;         // + lane*16 implicit (within buffer)
    const int lds1 = 4096 + wave * 1024;

    // Reader: lane fragment = 32 contiguous k-bytes of one row, as two b128s
    // at swizzled granules (2*lh)^s and (2*lh+1)^s.
    int offA[2][2], offB[2][2];
#pragma unroll
    for (int m = 0; m < 2; ++m) {
        int ra = wm * 64 + m * 32 + lr;
        int sa_ = (ra >> 1) & 3;
        offA[m][0] = ra * 64 + ((2 * lh + 0) ^ sa_) * 16;
        offA[m][1] = ra * 64 + ((2 * lh + 1) ^ sa_) * 16;
        int rb = wn * 64 + m * 32 + lr;
        int sb_ = (rb >> 1) & 3;
        offB[m][0] = rb * 64 + ((2 * lh + 0) ^ sb_) * 16;
        offB[m][1] = rb * 64 + ((2 * lh + 1) ^ sb_) * 16;
    }

    const int UNIT = 0x7F7F7F7F;  // e8m0 scale = 2^0 in all bytes

    auto stage = [&](int buf, int k0) {
        __builtin_amdgcn_global_load_lds((glb_u32_t*)(aSrc + off0 + k0),
                                         (lds_u32_t*)&sA[buf][lds0], 16, 0, 0);
        __builtin_amdgcn_global_load_lds((glb_u32_t*)(aSrc + off1 + k0),
                                         (lds_u32_t*)&sA[buf][lds1], 16, 0, 0);
        __builtin_amdgcn_global_load_lds((glb_u32_t*)(bSrc + off0 + k0),
                                         (lds_u32_t*)&sB[buf][lds0], 16, 0, 0);
        __builtin_amdgcn_global_load_lds((glb_u32_t*)(bSrc + off1 + k0),
                                         (lds_u32_t*)&sB[buf][lds1], 16, 0, 0);
    };
    auto compute = [&](int buf) {
        i32x8 a[2], b[2];
#pragma unroll
        for (int m = 0; m < 2; ++m) {
            i32x4 lo = *(const i32x4*)&sA[buf][offA[m][0]];
            i32x4 hi = *(const i32x4*)&sA[buf][offA[m][1]];
            a[m] = __builtin_shufflevector(lo, hi, 0, 1, 2, 3, 4, 5, 6, 7);
        }
#pragma unroll
        for (int n = 0; n < 2; ++n) {
            i32x4 lo = *(const i32x4*)&sB[buf][offB[n][0]];
            i32x4 hi = *(const i32x4*)&sB[buf][offB[n][1]];
            b[n] = __builtin_shufflevector(lo, hi, 0, 1, 2, 3, 4, 5, 6, 7);
        }
#pragma unroll
        for (int m = 0; m < 2; ++m)
#pragma unroll
            for (int n = 0; n < 2; ++n)
                acc[m][n] = __builtin_amdgcn_mfma_scale_f32_32x32x64_f8f6f4(
                    a[m], b[n], acc[m][n], 0, 0, 0, UNIT, 0, UNIT);
    };

    // prologue: tile 0 into buf 0
    stage(0, 0);
    __syncthreads();

    const int NT = HIDDEN / BK;   // 64
    for (int t = 0; t < NT; t += 2) {
        stage(1, (t + 1) * BK);           // next tile in flight during compute
        compute(0);
        __syncthreads();                  // vmcnt(0)+barrier: tile t+1 ready, buf0 free
        if (t + 2 < NT) stage(0, (t + 2) * BK);
        compute(1);
        __syncthreads();
    }

    const float wsc = *wscale_p;
#pragma unroll
    for (int m = 0; m < 2; ++m)
#pragma unroll
        for (int n = 0; n < 2; ++n) {
            const int col = bcol + wn * 64 + n * 32 + lr;
#pragma unroll
            for (int i = 0; i < 16; ++i) {
                const int rl = (i & 3) + 8 * (i >> 2) + 4 * lh;
                const int row_local = wm * 64 + m * 32 + rl;
                const float alpha = s_as[row_local] * wsc;
                const size_t o = (size_t)(brow + row_local) * HIDDEN + col;
                resid[o] += acc[m][n][i] * alpha;
            }
        }
}

// ---------------- launch ----------------
extern "C" void kernel_launch(void* const* d_in, const int* in_sizes, int n_in,
                              void* d_out, int out_size, void* d_ws, size_t ws_size,
                              hipStream_t stream) {
    const float* x   = (const float*)d_in[0];
    const float* nw  = (const float*)d_in[1];
    const float* Ws  = (const float*)d_in[2];
    const float* wsc = (const float*)d_in[3];
    float* out = (float*)d_out;

    uint8_t* ws = (uint8_t*)d_ws;
    float*   resid  = (float*)ws;                                  // 128 MiB
    uint8_t* yq     = ws + (size_t)TOKENS * HIDDEN * 4;            // 32 MiB
    uint8_t* Wq     = yq + (size_t)TOKENS * HIDDEN;                // 48 MiB
    float*   ascale = (float*)(Wq + (size_t)3 * HIDDEN * HIDDEN);  // 32 KiB

    // quantize weights (3 * H * H elements, 8 per thread)
    quant_weights<<<(3 * (size_t)HIDDEN * HIDDEN) / 2048, 256, 0, stream>>>(Ws, wsc, Wq);

    // relu + rmsnorm(norm_w[0]) + quant
    relu_rms_quant<<<TOKENS, 256, 0, stream>>>(x, nw, resid, yq, ascale);

    for (int i = 0; i < 3; ++i) {
        gemm_fp8<<<(TOKENS / BM) * (HIDDEN / BN), 256, 0, stream>>>(
            yq, Wq + (size_t)i * HIDDEN * HIDDEN, ascale, wsc + i, resid);
        if (i < 2)
            rms_quant<<<TOKENS, 256, 0, stream>>>(resid, nw + (size_t)(i + 1) * HIDDEN, yq, ascale);
        else
            rms_final<<<TOKENS, 256, 0, stream>>>(resid, nw + (size_t)3 * HIDDEN, out);
    }
}

// Round 5
// 691.022 us; speedup vs baseline: 2.7686x; 1.1411x over previous
//
#include <hip/hip_runtime.h>
#include <stdint.h>

#define TOKENS 8192
#define HIDDEN 4096
constexpr float EPS = 1e-6f;
constexpr float FP8_MAX = 448.0f;

using f32x4  = __attribute__((ext_vector_type(4))) float;
using f32x16 = __attribute__((ext_vector_type(16))) float;
using i32x4  = __attribute__((ext_vector_type(4))) int;
using i32x8  = __attribute__((ext_vector_type(8))) int;

typedef __attribute__((address_space(3))) uint32_t lds_u32_t;
typedef const __attribute__((address_space(1))) uint32_t glb_u32_t;

// ---------------- fp8 pack helper (OCP e4m3fn, RNE + saturate) ----------------
__device__ inline uint32_t pack_fp8x4(float a, float b, float c, float d) {
    int w = 0;
    w = __builtin_amdgcn_cvt_pk_fp8_f32(a, b, w, false); // bytes 0,1
    w = __builtin_amdgcn_cvt_pk_fp8_f32(c, d, w, true);  // bytes 2,3
    return (uint32_t)w;
}

// ---------------- block reductions (4 waves of 64) ----------------
__device__ inline float block_sum(float v, float* sh, int tid) {
#pragma unroll
    for (int o = 32; o > 0; o >>= 1) v += __shfl_xor(v, o, 64);
    if ((tid & 63) == 0) sh[tid >> 6] = v;
    __syncthreads();
    return sh[0] + sh[1] + sh[2] + sh[3];
}
__device__ inline float block_max(float v, float* sh, int tid) {
#pragma unroll
    for (int o = 32; o > 0; o >>= 1) v = fmaxf(v, __shfl_xor(v, o, 64));
    if ((tid & 63) == 0) sh[tid >> 6] = v;
    __syncthreads();
    return fmaxf(fmaxf(sh[0], sh[1]), fmaxf(sh[2], sh[3]));
}

// ---------------- weight quantization: Wq = fp8(W / s), linear layout ----------------
__launch_bounds__(256)
__global__ void quant_weights(const float* __restrict__ Ws,
                              const float* __restrict__ w_scales,
                              uint8_t* __restrict__ Wq) {
    size_t idx = ((size_t)blockIdx.x * 256 + threadIdx.x) * 8;
    int tensor = (int)(idx / ((size_t)HIDDEN * HIDDEN));
    float inv = 1.0f / w_scales[tensor];
    const float4* src = (const float4*)(Ws + idx);
    float4 v0 = src[0], v1 = src[1];
    uint2 out;
    out.x = pack_fp8x4(v0.x * inv, v0.y * inv, v0.z * inv, v0.w * inv);
    out.y = pack_fp8x4(v1.x * inv, v1.y * inv, v1.z * inv, v1.w * inv);
    *(uint2*)(Wq + idx) = out;
}

// ---------------- relu + rmsnorm + dynamic quant (layer 0 input) ----------------
__launch_bounds__(256)
__global__ void relu_rms_quant(const float* __restrict__ x,
                               const float* __restrict__ nw,   // norm_w row 0
                               float* __restrict__ resid,
                               uint8_t* __restrict__ yq,
                               float* __restrict__ ascale) {
    __shared__ float sh1[4], sh2[4];
    const int row = blockIdx.x, tid = threadIdx.x;
    const float* xr = x + (size_t)row * HIDDEN;
    float* rr = resid + (size_t)row * HIDDEN;

    float4 v[4];
    float ss = 0.f;
#pragma unroll
    for (int c = 0; c < 4; ++c) {
        float4 t = *(const float4*)(xr + c * 1024 + tid * 4);
        t.x = fmaxf(t.x, 0.f); t.y = fmaxf(t.y, 0.f);
        t.z = fmaxf(t.z, 0.f); t.w = fmaxf(t.w, 0.f);
        v[c] = t;
        ss += t.x * t.x + t.y * t.y + t.z * t.z + t.w * t.w;
        *(float4*)(rr + c * 1024 + tid * 4) = t;
    }
    ss = block_sum(ss, sh1, tid);
    float rstd = 1.0f / sqrtf(ss * (1.0f / HIDDEN) + EPS);

    float4 y[4];
    float amax = 0.f;
#pragma unroll
    for (int c = 0; c < 4; ++c) {
        float4 w = *(const float4*)(nw + c * 1024 + tid * 4);
        y[c].x = v[c].x * rstd * w.x; amax = fmaxf(amax, fabsf(y[c].x));
        y[c].y = v[c].y * rstd * w.y; amax = fmaxf(amax, fabsf(y[c].y));
        y[c].z = v[c].z * rstd * w.z; amax = fmaxf(amax, fabsf(y[c].z));
        y[c].w = v[c].w * rstd * w.w; amax = fmaxf(amax, fabsf(y[c].w));
    }
    amax = block_max(amax, sh2, tid);
    float s = fmaxf(amax / FP8_MAX, 1e-12f);
    if (tid == 0) ascale[row] = s;
    float inv = 1.0f / s;
#pragma unroll
    for (int c = 0; c < 4; ++c) {
        uint32_t p = pack_fp8x4(y[c].x * inv, y[c].y * inv, y[c].z * inv, y[c].w * inv);
        *(uint32_t*)(yq + (size_t)row * HIDDEN + c * 1024 + tid * 4) = p;
    }
}

// ---------------- rmsnorm + dynamic quant (between layers) ----------------
__launch_bounds__(256)
__global__ void rms_quant(const float* __restrict__ resid,
                          const float* __restrict__ nw,
                          uint8_t* __restrict__ yq,
                          float* __restrict__ ascale) {
    __shared__ float sh1[4], sh2[4];
    const int row = blockIdx.x, tid = threadIdx.x;
    const float* rr = resid + (size_t)row * HIDDEN;

    float4 v[4];
    float ss = 0.f;
#pragma unroll
    for (int c = 0; c < 4; ++c) {
        float4 t = *(const float4*)(rr + c * 1024 + tid * 4);
        v[c] = t;
        ss += t.x * t.x + t.y * t.y + t.z * t.z + t.w * t.w;
    }
    ss = block_sum(ss, sh1, tid);
    float rstd = 1.0f / sqrtf(ss * (1.0f / HIDDEN) + EPS);

    float4 y[4];
    float amax = 0.f;
#pragma unroll
    for (int c = 0; c < 4; ++c) {
        float4 w = *(const float4*)(nw + c * 1024 + tid * 4);
        y[c].x = v[c].x * rstd * w.x; amax = fmaxf(amax, fabsf(y[c].x));
        y[c].y = v[c].y * rstd * w.y; amax = fmaxf(amax, fabsf(y[c].y));
        y[c].z = v[c].z * rstd * w.z; amax = fmaxf(amax, fabsf(y[c].z));
        y[c].w = v[c].w * rstd * w.w; amax = fmaxf(amax, fabsf(y[c].w));
    }
    amax = block_max(amax, sh2, tid);
    float s = fmaxf(amax / FP8_MAX, 1e-12f);
    if (tid == 0) ascale[row] = s;
    float inv = 1.0f / s;
#pragma unroll
    for (int c = 0; c < 4; ++c) {
        uint32_t p = pack_fp8x4(y[c].x * inv, y[c].y * inv, y[c].z * inv, y[c].w * inv);
        *(uint32_t*)(yq + (size_t)row * HIDDEN + c * 1024 + tid * 4) = p;
    }
}

// ---------------- final rmsnorm -> f32 output ----------------
__launch_bounds__(256)
__global__ void rms_final(const float* __restrict__ resid,
                          const float* __restrict__ nw,
                          float* __restrict__ out) {
    __shared__ float sh1[4];
    const int row = blockIdx.x, tid = threadIdx.x;
    const float* rr = resid + (size_t)row * HIDDEN;

    float4 v[4];
    float ss = 0.f;
#pragma unroll
    for (int c = 0; c < 4; ++c) {
        float4 t = *(const float4*)(rr + c * 1024 + tid * 4);
        v[c] = t;
        ss += t.x * t.x + t.y * t.y + t.z * t.z + t.w * t.w;
    }
    ss = block_sum(ss, sh1, tid);
    float rstd = 1.0f / sqrtf(ss * (1.0f / HIDDEN) + EPS);

#pragma unroll
    for (int c = 0; c < 4; ++c) {
        float4 w = *(const float4*)(nw + c * 1024 + tid * 4);
        float4 o;
        o.x = v[c].x * rstd * w.x;
        o.y = v[c].y * rstd * w.y;
        o.z = v[c].z * rstd * w.z;
        o.w = v[c].w * rstd * w.w;
        *(float4*)(out + (size_t)row * HIDDEN + c * 1024 + tid * 4) = o;
    }
}

// ---------------- fp8 GEMM, 256x256 tile, depth-2 counted-vmcnt pipeline ----------------
// resid += a_scale[t]*w_scale * (Aq @ Bq^T), Aq/Bq linear row-major fp8.
// 8 waves (2m x 4n), per-wave output 128x64 = 4x2 MFMAs of 32x32x64 (MX-scaled, unit scale).
// 4 LDS buffers; per K-tile: stage(t+2) -> vmcnt(8) -> raw barrier -> ds_read+MFMA.
// vmcnt never drains to 0 in the main loop (T4); loads fly ~2 iterations.
// Race window analysis (1 barrier/iter, 4 buffers): between barrier(t) and barrier(t+1)
// the only LDS traffic is reads of buf[t&3] and stage-writes of buf[(t+3)&3] — disjoint.
#define BM 256
#define BN 256
#define BK 64
#define NBUF 4

__launch_bounds__(512, 2)
__global__ void gemm_fp8(const uint8_t* __restrict__ Aq,
                         const uint8_t* __restrict__ Bq,
                         const float* __restrict__ ascale,
                         const float* __restrict__ wscale_p,
                         float* __restrict__ resid) {
    __shared__ __align__(16) uint8_t sA[NBUF][BM * BK];   // 4 x 16 KB
    __shared__ __align__(16) uint8_t sB[NBUF][BN * BK];   // 4 x 16 KB
    __shared__ float s_as[BM];

    const int tid = threadIdx.x;
    // XCD-chunked bijective swizzle (grid = 512 = 8 * 64)
    int bid = blockIdx.x;
    bid = (bid & 7) * 64 + (bid >> 3);
    const int nbn = HIDDEN / BN;   // 16
    const int bm = bid / nbn, bn = bid % nbn;
    const int brow = bm * BM, bcol = bn * BN;

    const int wave = tid >> 6, lane = tid & 63;
    const int wm = wave >> 2, wn = wave & 3;   // 2 x 4 wave grid
    const int lr = lane & 31;      // row within 32x32 tile
    const int lh = lane >> 5;      // k-half (which 32B k-block)

    f32x16 acc[4][2] = {};

    const uint8_t* aSrc = Aq + (size_t)brow * HIDDEN;
    const uint8_t* bSrc = Bq + (size_t)bcol * HIDDEN;

    // Stager: issue c covers LDS bytes c*8192 + tid*16 -> row = c*128 + (tid>>2),
    // granule = tid&3. LDS[r][g] holds global granule g ^ ((r>>1)&3).
    // ((r+128)>>1)&3 == (r>>1)&3, so one gsrc serves both issues.
    const int r_st = tid >> 2;            // 0..127
    const int g_st = tid & 3;
    const int gsrc = g_st ^ ((r_st >> 1) & 3);
    const size_t off0 = (size_t)r_st * HIDDEN + gsrc * 16;
    const size_t off1 = (size_t)(r_st + 128) * HIDDEN + gsrc * 16;
    const int ldsw = wave * 1024;         // + lane*16 implicit (uniform base per wave)

    // Reader: lane fragment = 32 contiguous k-bytes of one row, two b128s at
    // swizzled granules (2*lh+h) ^ ((row>>1)&3).
    int offA[4][2], offB[2][2];
#pragma unroll
    for (int mi = 0; mi < 4; ++mi) {
        int ra = wm * 128 + mi * 32 + lr;
        int sw = (ra >> 1) & 3;
        offA[mi][0] = ra * 64 + ((2 * lh + 0) ^ sw) * 16;
        offA[mi][1] = ra * 64 + ((2 * lh + 1) ^ sw) * 16;
    }
#pragma unroll
    for (int ni = 0; ni < 2; ++ni) {
        int rb = wn * 64 + ni * 32 + lr;
        int sw = (rb >> 1) & 3;
        offB[ni][0] = rb * 64 + ((2 * lh + 0) ^ sw) * 16;
        offB[ni][1] = rb * 64 + ((2 * lh + 1) ^ sw) * 16;
    }

    const int UNIT = 0x7F7F7F7F;  // e8m0 scale = 2^0 in all bytes

    auto stage = [&](int buf, int kt) {
        const int k0 = kt * BK;
        __builtin_amdgcn_global_load_lds((glb_u32_t*)(aSrc + off0 + k0),
                                         (lds_u32_t*)&sA[buf][ldsw], 16, 0, 0);
        __builtin_amdgcn_global_load_lds((glb_u32_t*)(aSrc + off1 + k0),
                                         (lds_u32_t*)&sA[buf][8192 + ldsw], 16, 0, 0);
        __builtin_amdgcn_global_load_lds((glb_u32_t*)(bSrc + off0 + k0),
                                         (lds_u32_t*)&sB[buf][ldsw], 16, 0, 0);
        __builtin_amdgcn_global_load_lds((glb_u32_t*)(bSrc + off1 + k0),
                                         (lds_u32_t*)&sB[buf][8192 + ldsw], 16, 0, 0);
    };
    auto compute = [&](int buf) {
        i32x8 a[4], b[2];
#pragma unroll
        for (int mi = 0; mi < 4; ++mi) {
            i32x4 lo = *(const i32x4*)&sA[buf][offA[mi][0]];
            i32x4 hi = *(const i32x4*)&sA[buf][offA[mi][1]];
            a[mi] = __builtin_shufflevector(lo, hi, 0, 1, 2, 3, 4, 5, 6, 7);
        }
#pragma unroll
        for (int ni = 0; ni < 2; ++ni) {
            i32x4 lo = *(const i32x4*)&sB[buf][offB[ni][0]];
            i32x4 hi = *(const i32x4*)&sB[buf][offB[ni][1]];
            b[ni] = __builtin_shufflevector(lo, hi, 0, 1, 2, 3, 4, 5, 6, 7);
        }
        __builtin_amdgcn_s_setprio(1);
#pragma unroll
        for (int mi = 0; mi < 4; ++mi)
#pragma unroll
            for (int ni = 0; ni < 2; ++ni)
                acc[mi][ni] = __builtin_amdgcn_mfma_scale_f32_32x32x64_f8f6f4(
                    a[mi], b[ni], acc[mi][ni], 0, 0, 0, UNIT, 0, UNIT);
        __builtin_amdgcn_s_setprio(0);
    };

    const int NT = HIDDEN / BK;   // 64
    // prologue: tiles 0,1 in flight (8 loads)
    stage(0, 0);
    stage(1, 1);
    for (int t = 0; t < NT; ++t) {
        if (t + 2 < NT) {
            stage((t + 2) & 3, t + 2);                       // -> up to 12 outstanding
            asm volatile("s_waitcnt vmcnt(8)" ::: "memory"); // tile t's 4 loads landed
        } else if (t + 1 < NT) {
            asm volatile("s_waitcnt vmcnt(4)" ::: "memory");
        } else {
            asm volatile("s_waitcnt vmcnt(0)" ::: "memory");
        }
        __builtin_amdgcn_s_barrier();                        // all waves' tile-t loads visible
        compute(t & 3);
    }

    // epilogue: per-row activation scales via LDS
    if (tid < BM) s_as[tid] = ascale[brow + tid];
    __syncthreads();

    const float wsc = *wscale_p;
#pragma unroll
    for (int mi = 0; mi < 4; ++mi)
#pragma unroll
        for (int ni = 0; ni < 2; ++ni) {
            const int col = bcol + wn * 64 + ni * 32 + lr;
#pragma unroll
            for (int i = 0; i < 16; ++i) {
                const int rl = (i & 3) + 8 * (i >> 2) + 4 * lh;
                const int row_local = wm * 128 + mi * 32 + rl;
                const float alpha = s_as[row_local] * wsc;
                const size_t o = (size_t)(brow + row_local) * HIDDEN + col;
                resid[o] += acc[mi][ni][i] * alpha;
            }
        }
}

// ---------------- launch ----------------
extern "C" void kernel_launch(void* const* d_in, const int* in_sizes, int n_in,
                              void* d_out, int out_size, void* d_ws, size_t ws_size,
                              hipStream_t stream) {
    const float* x   = (const float*)d_in[0];
    const float* nw  = (const float*)d_in[1];
    const float* Ws  = (const float*)d_in[2];
    const float* wsc = (const float*)d_in[3];
    float* out = (float*)d_out;

    uint8_t* ws = (uint8_t*)d_ws;
    float*   resid  = (float*)ws;                                  // 128 MiB
    uint8_t* yq     = ws + (size_t)TOKENS * HIDDEN * 4;            // 32 MiB
    uint8_t* Wq     = yq + (size_t)TOKENS * HIDDEN;                // 48 MiB
    float*   ascale = (float*)(Wq + (size_t)3 * HIDDEN * HIDDEN);  // 32 KiB

    // quantize weights (3 * H * H elements, 8 per thread)
    quant_weights<<<(3 * (size_t)HIDDEN * HIDDEN) / 2048, 256, 0, stream>>>(Ws, wsc, Wq);

    // relu + rmsnorm(norm_w[0]) + quant
    relu_rms_quant<<<TOKENS, 256, 0, stream>>>(x, nw, resid, yq, ascale);

    for (int i = 0; i < 3; ++i) {
        gemm_fp8<<<(TOKENS / BM) * (HIDDEN / BN), 512, 0, stream>>>(
            yq, Wq + (size_t)i * HIDDEN * HIDDEN, ascale, wsc + i, resid);
        if (i < 2)
            rms_quant<<<TOKENS, 256, 0, stream>>>(resid, nw + (size_t)(i + 1) * HIDDEN, yq, ascale);
        else
            rms_final<<<TOKENS, 256, 0, stream>>>(resid, nw + (size_t)3 * HIDDEN, out);
    }
}